// Round 6
// baseline (12196.106 us; speedup 1.0000x reference)
//
#include <hip/hip_runtime.h>
#include <cstddef>
#include <math.h>

#define SEQ   256
#define BATCH 2048
#define FD    5
#define HD    64
#define NCOL  1280   // 256 gm cols + 1024 ga cols
#define NCOLE 1344   // + 64 attention cols (v = c_prev . W_att^T)
#define ROWS  4
#define NTHR  256
#define NBLK  (BATCH / ROWS)   // 512 blocks -> 2 blocks/CU

// Accurate libm-based activations (match jax/np fp32 to ~1-2 ulp).
// Fast __expf variants injected ~1e-6/step which the recurrence amplified to 8e-3 (round 1-2).
__device__ __forceinline__ float sigm(float x) { return 1.0f / (1.0f + expf(-x)); }
__device__ __forceinline__ float tanh_f(float x) { return tanhf(x); }

__device__ __forceinline__ float wave_sum(float v) {
#pragma unroll
    for (int m = 1; m < 64; m <<= 1) v += __shfl_xor(v, m);
    return v;
}

// UtE[c][h] contiguous per column:
//   c in [0,256):     U_main[:, c]
//   c in [256,1280):  U_aux[kk][:, gg], kk=(c-256)/128, gg=(c-256)%128
//   c in [1280,1344): W_att[c-1280, :]   (attention row; consumed against c1)
__global__ void transpose_u(const float* __restrict__ U_main,
                            const float* __restrict__ U_aux,
                            const float* __restrict__ W_att,
                            float* __restrict__ UtE) {
    const int c = blockIdx.x;
    const int h = threadIdx.x;
    float v;
    if (c < 256) {
        v = U_main[h * 256 + c];
    } else if (c < 1280) {
        int cp = c - 256, kk = cp >> 7, gg = cp & 127;
        v = U_aux[(size_t)kk * 64 * 128 + h * 128 + gg];
    } else {
        v = W_att[(c - 1280) * 64 + h];
    }
    UtE[c * 64 + h] = v;
}

// 2nd launch-bounds arg: (512,2) forced a 128-VGPR cap (16 waves/CU) and 56GB of spills
// in round 4. Here (256,2) -> 8 waves/CU co-residency target, 256-VGPR cap: harmless.
__global__ __launch_bounds__(NTHR, 2)
void minet_fused(const float* __restrict__ Y,
                 const float* __restrict__ x1, const float* __restrict__ x2,
                 const float* __restrict__ x3, const float* __restrict__ x4,
                 const float* __restrict__ x5, const float* __restrict__ x6,
                 const float* __restrict__ x7, const float* __restrict__ x8,
                 const float* __restrict__ W_main, const float* __restrict__ UtE,
                 const float* __restrict__ b_main, const float* __restrict__ W_aux,
                 const float* __restrict__ b_aux,  const float* __restrict__ b_att,
                 const float* __restrict__ W_ih,   const float* __restrict__ W_hh,
                 const float* __restrict__ b_ih,   const float* __restrict__ b_hh,
                 const float* __restrict__ lin_W,  const float* __restrict__ lin_b,
                 float* __restrict__ out)
{
    __shared__ __align__(16) float h1[ROWS][HD];
    __shared__ __align__(16) float c1[ROWS][HD];
    __shared__ __align__(16) float h2[ROWS][HD];
    __shared__ __align__(16) float outb[ROWS][NCOLE];      // 21 KB
    __shared__ __align__(16) float outg[2][ROWS][256];     // 8 KB
    __shared__ __align__(16) float inb[ROWS][9][8];        // 1.1 KB

    const int tid  = threadIdx.x;
    const int lane = tid & 63;
    const int wid  = tid >> 6;          // 4 waves; wave w owns batch row w in P5/P7
    const int b0   = blockIdx.x * ROWS;
    const bool isw0 = (tid < 64);       // wave 0 also computes the 64 attention cols

    // ---------- one-time setup ----------
    // 5 columns per thread: colv[j] = tid + 256*j  (j=0 -> main, j>=1 -> aux, uniform)
    float wf[5][5];
    float bias[5];
    int   inoff[5];
    const float* utp[5];
#pragma unroll
    for (int j = 0; j < 5; ++j) {
        const int c = tid + 256 * j;
        utp[j] = UtE + (size_t)c * 64;
        if (j == 0) {
#pragma unroll
            for (int f = 0; f < FD; ++f) wf[j][f] = W_main[f * 256 + c];
            bias[j]  = b_main[c];
            inoff[j] = 0;
        } else {
            int cp = c - 256, kk = cp >> 7, gg = cp & 127;
#pragma unroll
            for (int f = 0; f < FD; ++f) wf[j][f] = W_aux[(kk * 5 + f) * 128 + gg];
            bias[j]  = b_aux[kk * 128 + gg];
            inoff[j] = (1 + kk) * 8;
        }
    }
    const float* uta = UtE + (size_t)(1280 + tid) * 64;   // valid use only when isw0

    // LSTM2: threads 0..127 own W_ih cols {cc, cc+128} vs h1; 128..255 own W_hh cols vs h2
    const int  cc      = tid & 127;
    const bool ispart1 = (tid >= 128);
    const float* wbase = ispart1 ? W_hh : W_ih;
    const float* wcol0 = wbase + (size_t)cc * 64;
    const float* wcol1 = wbase + (size_t)(cc + 128) * 64;
    float b2[2];
    b2[0] = ispart1 ? 0.0f : (b_ih[cc] + b_hh[cc]);
    b2[1] = ispart1 ? 0.0f : (b_ih[cc + 128] + b_hh[cc + 128]);

    const float linw = lin_W[lane];
    const float linb = lin_b[0];
    const float batt = b_att[0];

    // zero states
    for (int i = tid; i < ROWS * HD; i += NTHR) {
        (&h1[0][0])[i] = 0.0f; (&c1[0][0])[i] = 0.0f; (&h2[0][0])[i] = 0.0f;
    }
    for (int i = tid; i < ROWS * 9 * 8; i += NTHR) (&inb[0][0][0])[i] = 0.0f;
    float c2 = 0.0f;   // LSTM2 cell (row=wid, unit=lane)

    // input prefetch: 180 values = 4 rows x 9 slots x 5 feats (threads 0..179)
    const bool pon = (tid < 180);
    const float* psrc = Y;
    int pofs = 0;
    float pf = 0.0f;
    if (pon) {
        int r = tid / 45, rem = tid % 45;
        int s = rem / 5, f = rem % 5;
        const float* base = Y;
        if (s == 1) base = x1; else if (s == 2) base = x2; else if (s == 3) base = x3;
        else if (s == 4) base = x4; else if (s == 5) base = x5; else if (s == 6) base = x6;
        else if (s == 7) base = x7; else if (s == 8) base = x8;
        psrc = base + (size_t)(b0 + r) * FD + f;
        pofs = (r * 9 + s) * 8 + f;
        pf   = psrc[0];   // t = 0
    }

    for (int t = 0; t < SEQ; ++t) {
        // ---- P1: publish staged inputs for step t
        if (pon) (&inb[0][0][0])[pofs] = pf;
        __syncthreads();   // BAR_A

        if (pon && t + 1 < SEQ) pf = psrc[(size_t)(t + 1) * BATCH * FD];

        // ---- P3: 1344-col dot. Regular cols: bias + in.wf + h1[r].UtE[c].
        //          Attention cols (wave 0): c1[r].W_att[hh,:]
        float acc[5][ROWS];
#pragma unroll
        for (int j = 0; j < 5; ++j) {
#pragma unroll
            for (int r = 0; r < ROWS; ++r) {
                const float* ip = &inb[r][0][0] + inoff[j];
                float4 ia = *(const float4*)ip;
                float  i4 = ip[4];
                acc[j][r] = bias[j] + ia.x * wf[j][0] + ia.y * wf[j][1] + ia.z * wf[j][2]
                                    + ia.w * wf[j][3] + i4 * wf[j][4];
            }
        }
        float vac[ROWS] = {0.0f, 0.0f, 0.0f, 0.0f};
#pragma unroll 2
        for (int hb = 0; hb < 16; ++hb) {
            float4 w0 = *(const float4*)(utp[0] + hb * 4);
            float4 w1 = *(const float4*)(utp[1] + hb * 4);
            float4 w2 = *(const float4*)(utp[2] + hb * 4);
            float4 w3 = *(const float4*)(utp[3] + hb * 4);
            float4 w4 = *(const float4*)(utp[4] + hb * 4);
            float4 wa;
            if (isw0) wa = *(const float4*)(uta + hb * 4);
#pragma unroll
            for (int r = 0; r < ROWS; ++r) {
                float4 h4 = *(const float4*)&h1[r][hb * 4];
                acc[0][r] = fmaf(h4.x, w0.x, fmaf(h4.y, w0.y,
                            fmaf(h4.z, w0.z, fmaf(h4.w, w0.w, acc[0][r]))));
                acc[1][r] = fmaf(h4.x, w1.x, fmaf(h4.y, w1.y,
                            fmaf(h4.z, w1.z, fmaf(h4.w, w1.w, acc[1][r]))));
                acc[2][r] = fmaf(h4.x, w2.x, fmaf(h4.y, w2.y,
                            fmaf(h4.z, w2.z, fmaf(h4.w, w2.w, acc[2][r]))));
                acc[3][r] = fmaf(h4.x, w3.x, fmaf(h4.y, w3.y,
                            fmaf(h4.z, w3.z, fmaf(h4.w, w3.w, acc[3][r]))));
                acc[4][r] = fmaf(h4.x, w4.x, fmaf(h4.y, w4.y,
                            fmaf(h4.z, w4.z, fmaf(h4.w, w4.w, acc[4][r]))));
                if (isw0) {
                    float4 c4 = *(const float4*)&c1[r][hb * 4];
                    vac[r] = fmaf(c4.x, wa.x, fmaf(c4.y, wa.y,
                             fmaf(c4.z, wa.z, fmaf(c4.w, wa.w, vac[r]))));
                }
            }
        }
#pragma unroll
        for (int j = 0; j < 5; ++j)
#pragma unroll
            for (int r = 0; r < ROWS; ++r)
                outb[r][tid + 256 * j] = acc[j][r];
        if (isw0) {
#pragma unroll
            for (int r = 0; r < ROWS; ++r)
                outb[r][1280 + tid] = vac[r];
        }
        __syncthreads();   // BAR_B: outb (incl. attention v) ready

        // ---- P5: gates + attention softmax + MI state update (wave wid -> row wid)
        {
            const int r = wid;
            const float v0 = outb[r][1280 + lane];
            float gi = outb[r][lane],       gf = outb[r][64 + lane];
            float go = outb[r][128 + lane], gc = outb[r][192 + lane];
            float ii = sigm(gi), ff = sigm(gf), oo = sigm(go), cm = tanh_f(gc);
            float l[9];
            l[0] = ii * cm;
#pragma unroll
            for (int k = 1; k <= 8; ++k) {
                float a_ = outb[r][256 + (k - 1) * 128 + lane];
                float b_ = outb[r][256 + (k - 1) * 128 + 64 + lane];
                l[k] = sigm(a_) * tanh_f(b_);
            }
            float u[9]; float umax = -1e30f;
#pragma unroll
            for (int k = 0; k < 9; ++k) {
                float p = wave_sum(l[k] * v0);
                u[k] = tanh_f(p + batt);
                umax = fmaxf(umax, u[k]);
            }
            float den = 0.0f, Lh = 0.0f;
#pragma unroll
            for (int k = 0; k < 9; ++k) {
                float e = expf(u[k] - umax);
                den += e;
                Lh = fmaf(e, l[k], Lh);
            }
            Lh /= den;
            float cp = c1[r][lane];
            float cn = fmaf(ff, cp, Lh);
            float hn = oo * tanh_f(cn);
            c1[r][lane] = cn;
            h1[r][lane] = hn;
        }
        __syncthreads();   // BAR_C: h1 (hs[t]) ready

        // ---- P6: LSTM2 pre-activations (2 cols/thread, one state source each half)
        {
            float accg[2][ROWS];
#pragma unroll
            for (int q = 0; q < 2; ++q)
#pragma unroll
                for (int r = 0; r < ROWS; ++r) accg[q][r] = b2[q];
            const float(*SS)[HD] = ispart1 ? h2 : h1;
#pragma unroll 4
            for (int hb = 0; hb < 16; ++hb) {
                float4 wA = *(const float4*)(wcol0 + hb * 4);
                float4 wB = *(const float4*)(wcol1 + hb * 4);
#pragma unroll
                for (int r = 0; r < ROWS; ++r) {
                    float4 s4 = *(const float4*)&SS[r][hb * 4];
                    accg[0][r] = fmaf(s4.x, wA.x, fmaf(s4.y, wA.y,
                                 fmaf(s4.z, wA.z, fmaf(s4.w, wA.w, accg[0][r]))));
                    accg[1][r] = fmaf(s4.x, wB.x, fmaf(s4.y, wB.y,
                                 fmaf(s4.z, wB.z, fmaf(s4.w, wB.w, accg[1][r]))));
                }
            }
            const int part = ispart1 ? 1 : 0;
#pragma unroll
            for (int r = 0; r < ROWS; ++r) {
                outg[part][r][cc]       = accg[0][r];
                outg[part][r][cc + 128] = accg[1][r];
            }
        }
        __syncthreads();   // BAR_D: outg ready

        // ---- P7: LSTM2 gates (torch order i,f,g,o) + output projection (row wid)
        {
            const int r = wid;
            float g0 = outg[0][r][lane]       + outg[1][r][lane];
            float g1 = outg[0][r][64 + lane]  + outg[1][r][64 + lane];
            float g2 = outg[0][r][128 + lane] + outg[1][r][128 + lane];
            float g3 = outg[0][r][192 + lane] + outg[1][r][192 + lane];
            float i2 = sigm(g0), f2 = sigm(g1), gg = tanh_f(g2), o2 = sigm(g3);
            float cn = fmaf(f2, c2, i2 * gg);
            c2 = cn;
            float hn = o2 * tanh_f(cn);
            h2[r][lane] = hn;
            float e = wave_sum(fmaxf(hn, 0.0f) * linw);
            if (lane == 0) out[(size_t)t * BATCH + b0 + r] = e + linb;
        }
        // next-iteration BAR_A separates h2 writes from P6 reads
    }
}

extern "C" void kernel_launch(void* const* d_in, const int* in_sizes, int n_in,
                              void* d_out, int out_size, void* d_ws, size_t ws_size,
                              hipStream_t stream) {
    const float* Y      = (const float*)d_in[0];
    const float* x1     = (const float*)d_in[1];
    const float* x2     = (const float*)d_in[2];
    const float* x3     = (const float*)d_in[3];
    const float* x4     = (const float*)d_in[4];
    const float* x5     = (const float*)d_in[5];
    const float* x6     = (const float*)d_in[6];
    const float* x7     = (const float*)d_in[7];
    const float* x8     = (const float*)d_in[8];
    const float* W_main = (const float*)d_in[9];
    const float* U_main = (const float*)d_in[10];
    const float* b_main = (const float*)d_in[11];
    const float* W_aux  = (const float*)d_in[12];
    const float* U_aux  = (const float*)d_in[13];
    const float* b_aux  = (const float*)d_in[14];
    const float* W_att  = (const float*)d_in[15];
    const float* b_att  = (const float*)d_in[16];
    const float* W_ih   = (const float*)d_in[17];
    const float* W_hh   = (const float*)d_in[18];
    const float* b_ih   = (const float*)d_in[19];
    const float* b_hh   = (const float*)d_in[20];
    const float* lin_W  = (const float*)d_in[21];
    const float* lin_b  = (const float*)d_in[22];
    float* out = (float*)d_out;
    float* UtE = (float*)d_ws;   // 1344*64 fp32 = 344 KB

    transpose_u<<<dim3(NCOLE), dim3(HD), 0, stream>>>(U_main, U_aux, W_att, UtE);

    dim3 grid(NBLK);    // 512 blocks -> 2 independent barrier groups per CU
    dim3 block(NTHR);   // 4 waves each
    minet_fused<<<grid, block, 0, stream>>>(Y, x1, x2, x3, x4, x5, x6, x7, x8,
                                            W_main, UtE, b_main, W_aux, b_aux,
                                            b_att, W_ih, W_hh, b_ih, b_hh,
                                            lin_W, lin_b, out);
}